// Round 1
// baseline (57.693 us; speedup 1.0000x reference)
//
#include <hip/hip_runtime.h>
#include <math.h>

#define NB 8
#define SEQ 4096
#define NBATCH 4
#define RPW 8  // query rows per wave

__device__ __forceinline__ float fexp2(float x) {
#if __has_builtin(__builtin_amdgcn_exp2f)
  return __builtin_amdgcn_exp2f(x);
#else
  return exp2f(x);
#endif
}

// ---------------------------------------------------------------------------
// Kernel 1: build the 8x8 clifford matrices + biases from w vectors.
// P layout (floats): [0..63] A = Mq*c0*0.5*log2e, [64..127] Mk, [128..191] Mv,
//                    [192..255] Mo, [256..263] bq' (folded), [264..271] bk,
//                    [272..279] bv, [280..287] bo
// ---------------------------------------------------------------------------
__global__ void ck_params(const float* __restrict__ wq, const float* __restrict__ bq,
                          const float* __restrict__ wk, const float* __restrict__ bk,
                          const float* __restrict__ wv, const float* __restrict__ bv,
                          const float* __restrict__ wo, const float* __restrict__ bo,
                          float* __restrict__ P) {
  const int blades[8] = {0, 1, 2, 4, 3, 5, 6, 7};  // also the bitmask->index map (self-inverse)
  int tid = threadIdx.x;
  if (tid >= 64) return;
  int j = tid >> 3, k = tid & 7;
  int bj = blades[j];
  float mq = 0.f, mk = 0.f, mv = 0.f, mo = 0.f;
  for (int i = 0; i < 8; ++i) {
    int ai = blades[i];
    int t = ai ^ bj;
    int kt = blades[t];  // idx[a_i ^ a_j]
    if (kt != k) continue;
    int cnt = 0, aa = ai >> 1;
    while (aa) { cnt += __popc(aa & bj); aa >>= 1; }
    float sgn = (cnt & 1) ? -1.f : 1.f;
    mq += sgn * wq[i]; mk += sgn * wk[i]; mv += sgn * wv[i]; mo += sgn * wo[i];
  }
  // c0 diagonal entry for blade k: sign of e_k * e_k
  int ak = blades[k];
  int cnt = 0, aa = ak >> 1;
  while (aa) { cnt += __popc(aa & ak); aa >>= 1; }
  float c0 = (cnt & 1) ? -1.f : 1.f;
  const float F = 0.72134752044448170368f;  // 0.5 * log2(e): folds /scale and exp->exp2
  P[tid]       = mq * c0 * F;
  P[64 + tid]  = mk;
  P[128 + tid] = mv;
  P[192 + tid] = mo;
  if (j == 0) {
    P[256 + k] = bq[k] * c0 * F;
    P[264 + k] = bk[k];
    P[272 + k] = bv[k];
    P[280 + k] = bo[k];
  }
}

// ---------------------------------------------------------------------------
// Kernel 2: Q''/K/V projections. One thread per token row.
// ---------------------------------------------------------------------------
__global__ __launch_bounds__(256) void ck_qkv(const float* __restrict__ x,
                                              const float* __restrict__ P,
                                              float* __restrict__ Qp,
                                              float* __restrict__ Kg,
                                              float* __restrict__ Vg) {
  int row = blockIdx.x * 256 + threadIdx.x;  // grid sized exactly to B*S
  const float4* x4 = (const float4*)(x + (size_t)row * 8);
  float4 xa = x4[0], xb = x4[1];
  float xr[8] = {xa.x, xa.y, xa.z, xa.w, xb.x, xb.y, xb.z, xb.w};
  float q[8], k[8], v[8];
#pragma unroll
  for (int c = 0; c < 8; ++c) { q[c] = P[256 + c]; k[c] = P[264 + c]; v[c] = P[272 + c]; }
#pragma unroll
  for (int j = 0; j < 8; ++j) {
    float xj = xr[j];
#pragma unroll
    for (int c = 0; c < 8; ++c) {
      q[c] = fmaf(xj, P[j * 8 + c], q[c]);
      k[c] = fmaf(xj, P[64 + j * 8 + c], k[c]);
      v[c] = fmaf(xj, P[128 + j * 8 + c], v[c]);
    }
  }
  float4* o4;
  o4 = (float4*)(Qp + (size_t)row * 8);
  o4[0] = make_float4(q[0], q[1], q[2], q[3]);
  o4[1] = make_float4(q[4], q[5], q[6], q[7]);
  o4 = (float4*)(Kg + (size_t)row * 8);
  o4[0] = make_float4(k[0], k[1], k[2], k[3]);
  o4[1] = make_float4(k[4], k[5], k[6], k[7]);
  o4 = (float4*)(Vg + (size_t)row * 8);
  o4[0] = make_float4(v[0], v[1], v[2], v[3]);
  o4[1] = make_float4(v[4], v[5], v[6], v[7]);
}

// ---------------------------------------------------------------------------
// Kernel 3: attention. One wave per RPW=8 consecutive query rows; lanes stride
// over t. No-max softmax (logits bounded, see analysis), exp2-native.
// Butterfly shfl_xor reduce, fused output clifford transform.
// ---------------------------------------------------------------------------
__global__ __launch_bounds__(256) void ck_attn(const float* __restrict__ Qp,
                                               const float* __restrict__ Kg,
                                               const float* __restrict__ Vg,
                                               const float* __restrict__ P,
                                               float* __restrict__ out) {
  int gtid = blockIdx.x * 256 + threadIdx.x;
  int wave = gtid >> 6;
  int lane = threadIdx.x & 63;
  int rowbase = wave * RPW;
  int b = rowbase >> 12;  // / SEQ
  const float* Kb = Kg + (size_t)b * SEQ * 8;
  const float* Vb = Vg + (size_t)b * SEQ * 8;

  float q[RPW][8];
#pragma unroll
  for (int r = 0; r < RPW; ++r) {
    const float4* q4 = (const float4*)(Qp + (size_t)(rowbase + r) * 8);
    float4 qa = q4[0], qb = q4[1];
    q[r][0] = qa.x; q[r][1] = qa.y; q[r][2] = qa.z; q[r][3] = qa.w;
    q[r][4] = qb.x; q[r][5] = qb.y; q[r][6] = qb.z; q[r][7] = qb.w;
  }
  float o[RPW][8];
  float l[RPW];
#pragma unroll
  for (int r = 0; r < RPW; ++r) {
    l[r] = 0.f;
#pragma unroll
    for (int c = 0; c < 8; ++c) o[r][c] = 0.f;
  }

  for (int t = lane; t < SEQ; t += 64) {
    const float4* k4 = (const float4*)(Kb + (size_t)t * 8);
    const float4* v4 = (const float4*)(Vb + (size_t)t * 8);
    float4 ka = k4[0], kb = k4[1];
    float4 va = v4[0], vb = v4[1];
    float kv[8] = {ka.x, ka.y, ka.z, ka.w, kb.x, kb.y, kb.z, kb.w};
    float vv[8] = {va.x, va.y, va.z, va.w, vb.x, vb.y, vb.z, vb.w};
#pragma unroll
    for (int r = 0; r < RPW; ++r) {
      float s = q[r][0] * kv[0];
#pragma unroll
      for (int c = 1; c < 8; ++c) s = fmaf(q[r][c], kv[c], s);
      float p = fexp2(s);  // logits pre-scaled to log2 domain
      l[r] += p;
#pragma unroll
      for (int c = 0; c < 8; ++c) o[r][c] = fmaf(p, vv[c], o[r][c]);
    }
  }

  // butterfly reduce (l, o[8]) per row across the 64 lanes
#pragma unroll
  for (int m = 1; m < 64; m <<= 1) {
#pragma unroll
    for (int r = 0; r < RPW; ++r) {
      l[r] += __shfl_xor(l[r], m, 64);
#pragma unroll
      for (int c = 0; c < 8; ++c) o[r][c] += __shfl_xor(o[r][c], m, 64);
    }
  }

  // lanes 0..7 each produce one output blade k for all RPW rows:
  // out[k] = bo[k] + sum_j (O_j / L) * Mo[j][k]
  if (lane < 8) {
    int k = lane;
    float moc[8];
#pragma unroll
    for (int j2 = 0; j2 < 8; ++j2) moc[j2] = P[192 + j2 * 8 + k];
    float bok = P[280 + k];
#pragma unroll
    for (int r = 0; r < RPW; ++r) {
      float inv = 1.f / l[r];
      float acc = bok;
#pragma unroll
      for (int j2 = 0; j2 < 8; ++j2) acc = fmaf(o[r][j2] * inv, moc[j2], acc);
      out[(size_t)(rowbase + r) * 8 + k] = acc;
    }
  }
}

// ---------------------------------------------------------------------------
extern "C" void kernel_launch(void* const* d_in, const int* in_sizes, int n_in,
                              void* d_out, int out_size, void* d_ws, size_t ws_size,
                              hipStream_t stream) {
  const float* x  = (const float*)d_in[0];
  const float* wq = (const float*)d_in[1];
  const float* bq = (const float*)d_in[2];
  const float* wk = (const float*)d_in[3];
  const float* bk = (const float*)d_in[4];
  const float* wv = (const float*)d_in[5];
  const float* bv = (const float*)d_in[6];
  const float* wo = (const float*)d_in[7];
  const float* bo = (const float*)d_in[8];

  float* P  = (float*)d_ws;                 // 288 floats (padded to 512)
  float* Qp = P + 512;                      // B*S*8
  float* Kg = Qp + NBATCH * SEQ * 8;        // B*S*8
  float* Vg = Kg + NBATCH * SEQ * 8;        // B*S*8; total ws ~1.58 MB
  float* outp = (float*)d_out;

  hipLaunchKernelGGL(ck_params, dim3(1), dim3(64), 0, stream,
                     wq, bq, wk, bk, wv, bv, wo, bo, P);
  hipLaunchKernelGGL(ck_qkv, dim3(NBATCH * SEQ / 256), dim3(256), 0, stream,
                     x, P, Qp, Kg, Vg);
  hipLaunchKernelGGL(ck_attn, dim3(NBATCH * SEQ / (RPW * 4)), dim3(256), 0, stream,
                     Qp, Kg, Vg, P, outp);
}

// Round 2
// 51.284 us; speedup vs baseline: 1.1250x; 1.1250x over previous
//
#include <hip/hip_runtime.h>
#include <math.h>

#define NB 8
#define SEQ 4096
#define NBATCH 4
#define RPW 8     // query rows per block
#define TSPLIT 4  // waves per block, each takes SEQ/TSPLIT of t

__device__ __forceinline__ float fexp2(float x) {
#if __has_builtin(__builtin_amdgcn_exp2f)
  return __builtin_amdgcn_exp2f(x);
#else
  return exp2f(x);
#endif
}

// ---------------------------------------------------------------------------
// Kernel 1: build the 8x8 clifford matrices + biases from w vectors.
// P layout (floats): [0..63] A = Mq*c0*0.5*log2e, [64..127] Mk, [128..191] Mv,
//                    [192..255] Mo, [256..263] bq' (folded), [264..271] bk,
//                    [272..279] bv, [280..287] bo
// ---------------------------------------------------------------------------
__global__ void ck_params(const float* __restrict__ wq, const float* __restrict__ bq,
                          const float* __restrict__ wk, const float* __restrict__ bk,
                          const float* __restrict__ wv, const float* __restrict__ bv,
                          const float* __restrict__ wo, const float* __restrict__ bo,
                          float* __restrict__ P) {
  const int blades[8] = {0, 1, 2, 4, 3, 5, 6, 7};  // bitmask<->index map (self-inverse)
  int tid = threadIdx.x;
  if (tid >= 64) return;
  int j = tid >> 3, k = tid & 7;
  int bj = blades[j];
  float mq = 0.f, mk = 0.f, mv = 0.f, mo = 0.f;
  for (int i = 0; i < 8; ++i) {
    int ai = blades[i];
    int t = ai ^ bj;
    int kt = blades[t];  // idx[a_i ^ a_j]
    if (kt != k) continue;
    int cnt = 0, aa = ai >> 1;
    while (aa) { cnt += __popc(aa & bj); aa >>= 1; }
    float sgn = (cnt & 1) ? -1.f : 1.f;
    mq += sgn * wq[i]; mk += sgn * wk[i]; mv += sgn * wv[i]; mo += sgn * wo[i];
  }
  // c0 diagonal entry for blade k: sign of e_k * e_k
  int ak = blades[k];
  int cnt = 0, aa = ak >> 1;
  while (aa) { cnt += __popc(aa & ak); aa >>= 1; }
  float c0 = (cnt & 1) ? -1.f : 1.f;
  const float F = 0.72134752044448170368f;  // 0.5 * log2(e): folds /scale and exp->exp2
  P[tid]       = mq * c0 * F;
  P[64 + tid]  = mk;
  P[128 + tid] = mv;
  P[192 + tid] = mo;
  if (j == 0) {
    P[256 + k] = bq[k] * c0 * F;
    P[264 + k] = bk[k];
    P[272 + k] = bv[k];
    P[280 + k] = bo[k];
  }
}

// ---------------------------------------------------------------------------
// Kernel 2: Q''/K/V projections. One thread per token row.
// ---------------------------------------------------------------------------
__global__ __launch_bounds__(256) void ck_qkv(const float* __restrict__ x,
                                              const float* __restrict__ P,
                                              float* __restrict__ Qp,
                                              float* __restrict__ Kg,
                                              float* __restrict__ Vg) {
  int row = blockIdx.x * 256 + threadIdx.x;  // grid sized exactly to B*S
  const float4* x4 = (const float4*)(x + (size_t)row * 8);
  float4 xa = x4[0], xb = x4[1];
  float xr[8] = {xa.x, xa.y, xa.z, xa.w, xb.x, xb.y, xb.z, xb.w};
  float q[8], k[8], v[8];
#pragma unroll
  for (int c = 0; c < 8; ++c) { q[c] = P[256 + c]; k[c] = P[264 + c]; v[c] = P[272 + c]; }
#pragma unroll
  for (int j = 0; j < 8; ++j) {
    float xj = xr[j];
#pragma unroll
    for (int c = 0; c < 8; ++c) {
      q[c] = fmaf(xj, P[j * 8 + c], q[c]);
      k[c] = fmaf(xj, P[64 + j * 8 + c], k[c]);
      v[c] = fmaf(xj, P[128 + j * 8 + c], v[c]);
    }
  }
  float4* o4;
  o4 = (float4*)(Qp + (size_t)row * 8);
  o4[0] = make_float4(q[0], q[1], q[2], q[3]);
  o4[1] = make_float4(q[4], q[5], q[6], q[7]);
  o4 = (float4*)(Kg + (size_t)row * 8);
  o4[0] = make_float4(k[0], k[1], k[2], k[3]);
  o4[1] = make_float4(k[4], k[5], k[6], k[7]);
  o4 = (float4*)(Vg + (size_t)row * 8);
  o4[0] = make_float4(v[0], v[1], v[2], v[3]);
  o4[1] = make_float4(v[4], v[5], v[6], v[7]);
}

// ---------------------------------------------------------------------------
// Kernel 3: attention. One BLOCK per RPW=8 query rows; 4 waves split the
// t-range (1024 each); lanes stride t within a wave. No-max softmax (logits
// bounded in log2 domain), exp2-native. 3-step butterfly -> LDS partials ->
// parallel final reduce + fused output clifford transform.
// ---------------------------------------------------------------------------
__global__ __launch_bounds__(256) void ck_attn(const float* __restrict__ Qp,
                                               const float* __restrict__ Kg,
                                               const float* __restrict__ Vg,
                                               const float* __restrict__ P,
                                               float* __restrict__ out) {
  // [wave][8-lane group][row][l, o0..7], inner padded to 10 floats
  __shared__ float L1[TSPLIT][8][RPW][10];
  __shared__ float L2[RPW][9];

  const int tid = threadIdx.x;
  const int w = tid >> 6;
  const int lane = tid & 63;
  const int rowbase = blockIdx.x * RPW;
  const int b = rowbase >> 12;  // / SEQ
  const float* Kb = Kg + (size_t)b * SEQ * 8;
  const float* Vb = Vg + (size_t)b * SEQ * 8;

  float q[RPW][8];
#pragma unroll
  for (int r = 0; r < RPW; ++r) {
    const float4* q4 = (const float4*)(Qp + (size_t)(rowbase + r) * 8);
    float4 qa = q4[0], qb = q4[1];
    q[r][0] = qa.x; q[r][1] = qa.y; q[r][2] = qa.z; q[r][3] = qa.w;
    q[r][4] = qb.x; q[r][5] = qb.y; q[r][6] = qb.z; q[r][7] = qb.w;
  }
  float o[RPW][8];
  float l[RPW];
#pragma unroll
  for (int r = 0; r < RPW; ++r) {
    l[r] = 0.f;
#pragma unroll
    for (int c = 0; c < 8; ++c) o[r][c] = 0.f;
  }

  const int t0 = w * (SEQ / TSPLIT) + lane;
#pragma unroll 2
  for (int i = 0; i < SEQ / TSPLIT / 64; ++i) {
    int t = t0 + i * 64;
    const float4* k4 = (const float4*)(Kb + (size_t)t * 8);
    const float4* v4 = (const float4*)(Vb + (size_t)t * 8);
    float4 ka = k4[0], kb = k4[1];
    float4 va = v4[0], vb = v4[1];
    float kv[8] = {ka.x, ka.y, ka.z, ka.w, kb.x, kb.y, kb.z, kb.w};
    float vv[8] = {va.x, va.y, va.z, va.w, vb.x, vb.y, vb.z, vb.w};
#pragma unroll
    for (int r = 0; r < RPW; ++r) {
      float s = q[r][0] * kv[0];
#pragma unroll
      for (int c = 1; c < 8; ++c) s = fmaf(q[r][c], kv[c], s);
      float p = fexp2(s);  // logits pre-scaled to log2 domain
      l[r] += p;
#pragma unroll
      for (int c = 0; c < 8; ++c) o[r][c] = fmaf(p, vv[c], o[r][c]);
    }
  }

  // 3-step butterfly: every 8-lane group ends up with the group's sums
#pragma unroll
  for (int m = 1; m <= 4; m <<= 1) {
#pragma unroll
    for (int r = 0; r < RPW; ++r) {
      l[r] += __shfl_xor(l[r], m, 64);
#pragma unroll
      for (int c = 0; c < 8; ++c) o[r][c] += __shfl_xor(o[r][c], m, 64);
    }
  }

  // lane slot s in each group writes row s's partials (static reg indices only)
  {
    const int g = lane >> 3;
    const int slot = lane & 7;
#pragma unroll
    for (int r = 0; r < RPW; ++r) {
      if (slot == r) {
        L1[w][g][r][0] = l[r];
#pragma unroll
        for (int c = 0; c < 8; ++c) L1[w][g][r][1 + c] = o[r][c];
      }
    }
  }
  __syncthreads();

  // stage A: sum the 32 partials per (row, value)
  if (tid < 64) {
    int row = tid >> 3, j = tid & 7;
    float s = 0.f;
#pragma unroll
    for (int w2 = 0; w2 < TSPLIT; ++w2)
#pragma unroll
      for (int g2 = 0; g2 < 8; ++g2) s += L1[w2][g2][row][1 + j];
    L2[row][j] = s;
  } else if (tid < 64 + RPW) {
    int row = tid - 64;
    float s = 0.f;
#pragma unroll
    for (int w2 = 0; w2 < TSPLIT; ++w2)
#pragma unroll
      for (int g2 = 0; g2 < 8; ++g2) s += L1[w2][g2][row][0];
    L2[row][8] = s;
  }
  __syncthreads();

  // stage B: normalize + fused output clifford transform
  if (tid < 64) {
    int row = tid >> 3, k = tid & 7;
    float inv = 1.f / L2[row][8];
    float acc = P[280 + k];
#pragma unroll
    for (int j = 0; j < 8; ++j) acc = fmaf(L2[row][j] * inv, P[192 + j * 8 + k], acc);
    out[(size_t)(rowbase + row) * 8 + k] = acc;
  }
}

// ---------------------------------------------------------------------------
extern "C" void kernel_launch(void* const* d_in, const int* in_sizes, int n_in,
                              void* d_out, int out_size, void* d_ws, size_t ws_size,
                              hipStream_t stream) {
  const float* x  = (const float*)d_in[0];
  const float* wq = (const float*)d_in[1];
  const float* bq = (const float*)d_in[2];
  const float* wk = (const float*)d_in[3];
  const float* bk = (const float*)d_in[4];
  const float* wv = (const float*)d_in[5];
  const float* bv = (const float*)d_in[6];
  const float* wo = (const float*)d_in[7];
  const float* bo = (const float*)d_in[8];

  float* P  = (float*)d_ws;                 // 288 floats (padded to 512)
  float* Qp = P + 512;                      // B*S*8
  float* Kg = Qp + NBATCH * SEQ * 8;        // B*S*8
  float* Vg = Kg + NBATCH * SEQ * 8;        // B*S*8; total ws ~1.58 MB
  float* outp = (float*)d_out;

  hipLaunchKernelGGL(ck_params, dim3(1), dim3(64), 0, stream,
                     wq, bq, wk, bk, wv, bv, wo, bo, P);
  hipLaunchKernelGGL(ck_qkv, dim3(NBATCH * SEQ / 256), dim3(256), 0, stream,
                     x, P, Qp, Kg, Vg);
  hipLaunchKernelGGL(ck_attn, dim3(NBATCH * SEQ / RPW), dim3(256), 0, stream,
                     Qp, Kg, Vg, P, outp);
}

// Round 4
// 27.210 us; speedup vs baseline: 2.1203x; 1.8848x over previous
//
#include <hip/hip_runtime.h>
#include <math.h>

#define SEQ 4096
#define NBATCH 4
#define SGRP 64      // s-rows per attn block
#define TWAVES 16    // waves per attn block (t-split)
#define TCHUNK (SEQ / TWAVES)  // 256 t per wave
#define TT 16        // t-tile size

typedef _Float16 f16;
typedef __attribute__((ext_vector_type(4))) _Float16 f16x4;
typedef __attribute__((ext_vector_type(8))) _Float16 f16x8;
typedef __attribute__((ext_vector_type(4))) float f32x4;
typedef __attribute__((ext_vector_type(4))) short s16x4;

__device__ __forceinline__ float fexp2(float x) {
#if __has_builtin(__builtin_amdgcn_exp2f)
  return __builtin_amdgcn_exp2f(x);
#else
  return exp2f(x);
#endif
}

// float -> bf16 bits, round-to-nearest-even. bf16 has f32 exponent range:
// exp2() of ANY logit stays finite (the f16 version NaN'd on diagonal
// quadratic-form logits >= 16 in log2 domain -> inf*-inf in PV MFMA).
__device__ __forceinline__ unsigned short f2bf(float f) {
  unsigned u = __builtin_bit_cast(unsigned, f);
  u += 0x7FFF + ((u >> 16) & 1);
  return (unsigned short)(u >> 16);
}

// ---------------------------------------------------------------------------
// Kernel 1: build the 8x8 clifford matrices + biases from w vectors.
// P layout (floats): [0..63] Mq*c0*0.5*log2e, [64..127] Mk, [128..191] Mv,
//                    [192..255] Mo, [256..263] bq', [264..271] bk,
//                    [272..279] bv, [280..287] bo
// ---------------------------------------------------------------------------
__global__ void ck_params(const float* __restrict__ wq, const float* __restrict__ bq,
                          const float* __restrict__ wk, const float* __restrict__ bk,
                          const float* __restrict__ wv, const float* __restrict__ bv,
                          const float* __restrict__ wo, const float* __restrict__ bo,
                          float* __restrict__ P) {
  const int blades[8] = {0, 1, 2, 4, 3, 5, 6, 7};  // bitmask<->index map (self-inverse)
  int tid = threadIdx.x;
  if (tid >= 64) return;
  int j = tid >> 3, k = tid & 7;
  int bj = blades[j];
  float mq = 0.f, mk = 0.f, mv = 0.f, mo = 0.f;
  for (int i = 0; i < 8; ++i) {
    int ai = blades[i];
    int t = ai ^ bj;
    int kt = blades[t];  // idx[a_i ^ a_j]
    if (kt != k) continue;
    int cnt = 0, aa = ai >> 1;
    while (aa) { cnt += __popc(aa & bj); aa >>= 1; }
    float sgn = (cnt & 1) ? -1.f : 1.f;
    mq += sgn * wq[i]; mk += sgn * wk[i]; mv += sgn * wv[i]; mo += sgn * wo[i];
  }
  // c0 diagonal entry for blade k: sign of e_k * e_k
  int ak = blades[k];
  int cnt = 0, aa = ak >> 1;
  while (aa) { cnt += __popc(aa & ak); aa >>= 1; }
  float c0 = (cnt & 1) ? -1.f : 1.f;
  const float F = 0.72134752044448170368f;  // 0.5 * log2(e)
  P[tid]       = mq * c0 * F;
  P[64 + tid]  = mk;
  P[128 + tid] = mv;
  P[192 + tid] = mo;
  if (j == 0) {
    P[256 + k] = bq[k] * c0 * F;
    P[264 + k] = bk[k];
    P[272 + k] = bv[k];
    P[280 + k] = bo[k];
  }
}

// ---------------------------------------------------------------------------
// Kernel 2: projections + packing for the MFMA attention.
//  Qp[row][16] f16 = [qhi(8) | qlo(8)]   (B-operand rows; hi/lo split)
//  Kp[row][16] f16 = [khi(8) | khi(8)]   (A-operand rows; with [qhi|qlo]
//                                         one K=16 MFMA gives khi·(qhi+qlo))
//  Vt[b][c][t] bf16 bits: rows 0-7 = V blades, row 8 = ones (softmax denom),
//                         rows 9-15 = 0
// ---------------------------------------------------------------------------
__global__ __launch_bounds__(64) void ck_qkv(const float* __restrict__ x,
                                             const float* __restrict__ P,
                                             f16* __restrict__ Qp,
                                             f16* __restrict__ Kp,
                                             unsigned short* __restrict__ Vt) {
  int row = blockIdx.x * 64 + threadIdx.x;  // grid sized exactly to B*S
  int b = row >> 12;
  int s = row & (SEQ - 1);
  const float4* x4 = (const float4*)(x + (size_t)row * 8);
  float4 xa = x4[0], xb = x4[1];
  float xr[8] = {xa.x, xa.y, xa.z, xa.w, xb.x, xb.y, xb.z, xb.w};
  float q[8], k[8], v[8];
#pragma unroll
  for (int c = 0; c < 8; ++c) { q[c] = P[256 + c]; k[c] = P[264 + c]; v[c] = P[272 + c]; }
#pragma unroll
  for (int j = 0; j < 8; ++j) {
    float xj = xr[j];
#pragma unroll
    for (int c = 0; c < 8; ++c) {
      q[c] = fmaf(xj, P[j * 8 + c], q[c]);
      k[c] = fmaf(xj, P[64 + j * 8 + c], k[c]);
      v[c] = fmaf(xj, P[128 + j * 8 + c], v[c]);
    }
  }
  f16x8 qa, qb, ka;
#pragma unroll
  for (int c = 0; c < 8; ++c) {
    f16 h = (f16)q[c];
    qa[c] = h;
    qb[c] = (f16)(q[c] - (float)h);
    ka[c] = (f16)k[c];
  }
  f16x8* qrow = (f16x8*)(Qp + (size_t)row * 16);
  qrow[0] = qa; qrow[1] = qb;
  f16x8* krow = (f16x8*)(Kp + (size_t)row * 16);
  krow[0] = ka; krow[1] = ka;
  unsigned short* vtb = Vt + (size_t)b * 16 * SEQ;
#pragma unroll
  for (int c = 0; c < 8; ++c) vtb[c * SEQ + s] = f2bf(v[c]);
  vtb[8 * SEQ + s] = 0x3F80;  // 1.0 bf16
#pragma unroll
  for (int c = 9; c < 16; ++c) vtb[c * SEQ + s] = 0;
}

// ---------------------------------------------------------------------------
// Kernel 3: MFMA flash attention, no-max softmax (bf16 P has f32 exponent
// range -> no overflow for any logit). One block = 64 s-rows; 16 waves
// t-split (256 t each). Per wave, per 16-t tile, per 16-s subtile g:
//   S^T = mfma_16x16x16f16(Kfrag, Qfrag[g], 0)
//     -> lane holds S[s=l&15][t0 + 4*(l>>4)+r], r=0..3
//   P = exp2(S) elementwise, f32 -> bf16  (exactly the B-frag of P^T for PV)
//   accT[g] = mfma_16x16x16bf16_1k(VaugTfrag, Pfrag, accT[g])
//     -> lane holds O^T[c=4*(l>>4)+r][s=l&15]; row c=8 is the denom l.
// Combine the 16 wave-partials in LDS, normalize, fuse Mo clifford transform.
// ---------------------------------------------------------------------------
__global__ __launch_bounds__(1024) void ck_attn(const f16* __restrict__ Qp,
                                                const f16* __restrict__ Kp,
                                                const unsigned short* __restrict__ Vt,
                                                const float* __restrict__ P,
                                                float* __restrict__ out) {
  __shared__ float Lo[TWAVES][SGRP][9];

  const int tid = threadIdx.x;
  const int w = tid >> 6;
  const int lane = tid & 63;
  const int lo = lane & 15, hi = lane >> 4;
  const int rowbase = blockIdx.x * SGRP;
  const int b = rowbase >> 12;

  // Q fragments for the 4 s-subtiles (hoisted)
  f16x4 qf0 = *(const f16x4*)(Qp + (size_t)(rowbase + 0 * 16 + lo) * 16 + 4 * hi);
  f16x4 qf1 = *(const f16x4*)(Qp + (size_t)(rowbase + 1 * 16 + lo) * 16 + 4 * hi);
  f16x4 qf2 = *(const f16x4*)(Qp + (size_t)(rowbase + 2 * 16 + lo) * 16 + 4 * hi);
  f16x4 qf3 = *(const f16x4*)(Qp + (size_t)(rowbase + 3 * 16 + lo) * 16 + 4 * hi);

  f32x4 acc0 = {0.f, 0.f, 0.f, 0.f};
  f32x4 acc1 = acc0, acc2 = acc0, acc3 = acc0;
  const f32x4 zero = {0.f, 0.f, 0.f, 0.f};

  const f16* kbase = Kp + ((size_t)b * SEQ + w * TCHUNK + lo) * 16 + 4 * hi;
  const unsigned short* vbase = Vt + ((size_t)b * 16 + lo) * SEQ + w * TCHUNK + 4 * hi;

#pragma unroll 2
  for (int it = 0; it < TCHUNK / TT; ++it) {
    f16x4 kf = *(const f16x4*)(kbase + it * TT * 16);
    s16x4 vf = *(const s16x4*)(vbase + it * TT);

#define SUBTILE(QF, ACC)                                                     \
    {                                                                        \
      f32x4 s4 = __builtin_amdgcn_mfma_f32_16x16x16f16(kf, QF, zero, 0, 0, 0); \
      s16x4 pf;                                                              \
      pf[0] = (short)f2bf(fexp2(s4[0]));                                     \
      pf[1] = (short)f2bf(fexp2(s4[1]));                                     \
      pf[2] = (short)f2bf(fexp2(s4[2]));                                     \
      pf[3] = (short)f2bf(fexp2(s4[3]));                                     \
      ACC = __builtin_amdgcn_mfma_f32_16x16x16bf16_1k(vf, pf, ACC, 0, 0, 0); \
    }
    SUBTILE(qf0, acc0)
    SUBTILE(qf1, acc1)
    SUBTILE(qf2, acc2)
    SUBTILE(qf3, acc3)
#undef SUBTILE
  }

  // write wave partials: lanes hi<2 carry O blades 0-7, lane hi==2,r=0 carries l
#define WRITEG(G, ACC)                                                       \
  {                                                                          \
    if (hi < 2) {                                                            \
      Lo[w][G * 16 + lo][4 * hi + 0] = ACC[0];                               \
      Lo[w][G * 16 + lo][4 * hi + 1] = ACC[1];                               \
      Lo[w][G * 16 + lo][4 * hi + 2] = ACC[2];                               \
      Lo[w][G * 16 + lo][4 * hi + 3] = ACC[3];                               \
    } else if (hi == 2) {                                                    \
      Lo[w][G * 16 + lo][8] = ACC[0];                                        \
    }                                                                        \
  }
  WRITEG(0, acc0)
  WRITEG(1, acc1)
  WRITEG(2, acc2)
  WRITEG(3, acc3)
#undef WRITEG
  __syncthreads();

  // stage 1: sum 16 wave-partials per (s, j); result kept in Lo[0]
  if (tid < SGRP * 9) {
    int s = tid / 9, j = tid - s * 9;
    float sum = 0.f;
#pragma unroll
    for (int w2 = 0; w2 < TWAVES; ++w2) sum += Lo[w2][s][j];
    Lo[0][s][j] = sum;  // only this thread touches column (s,j)
  }
  __syncthreads();

  // stage 2: normalize + fused output clifford transform
  if (tid < SGRP * 8) {
    int s = tid >> 3, ko = tid & 7;
    float inv = 1.f / Lo[0][s][8];
    float a = P[280 + ko];
#pragma unroll
    for (int j = 0; j < 8; ++j) a = fmaf(Lo[0][s][j] * inv, P[192 + j * 8 + ko], a);
    out[(size_t)(rowbase + s) * 8 + ko] = a;
  }
}

// ---------------------------------------------------------------------------
extern "C" void kernel_launch(void* const* d_in, const int* in_sizes, int n_in,
                              void* d_out, int out_size, void* d_ws, size_t ws_size,
                              hipStream_t stream) {
  const float* x  = (const float*)d_in[0];
  const float* wq = (const float*)d_in[1];
  const float* bq = (const float*)d_in[2];
  const float* wk = (const float*)d_in[3];
  const float* bk = (const float*)d_in[4];
  const float* wv = (const float*)d_in[5];
  const float* bv = (const float*)d_in[6];
  const float* wo = (const float*)d_in[7];
  const float* bo = (const float*)d_in[8];

  float* P = (float*)d_ws;                              // 288 floats (padded to 512)
  f16* Qp = (f16*)(P + 512);                            // [B*S][16] f16 = 512 KB
  f16* Kp = Qp + (size_t)NBATCH * SEQ * 16;             // [B*S][16] f16 = 512 KB
  unsigned short* Vt = (unsigned short*)(Kp + (size_t)NBATCH * SEQ * 16);  // [B][16][S] bf16 = 512 KB
  float* outp = (float*)d_out;

  hipLaunchKernelGGL(ck_params, dim3(1), dim3(64), 0, stream,
                     wq, bq, wk, bk, wv, bv, wo, bo, P);
  hipLaunchKernelGGL(ck_qkv, dim3(NBATCH * SEQ / 64), dim3(64), 0, stream,
                     x, P, Qp, Kp, Vt);
  hipLaunchKernelGGL(ck_attn, dim3(NBATCH * SEQ / SGRP), dim3(1024), 0, stream,
                     Qp, Kp, Vt, P, outp);
}

// Round 5
// 26.832 us; speedup vs baseline: 2.1501x; 1.0141x over previous
//
#include <hip/hip_runtime.h>
#include <math.h>

#define SEQ 4096
#define NBATCH 4
#define SGRP 32      // s-rows per attn block
#define TWAVES 16    // waves per attn block (t-split)
#define TCHUNK (SEQ / TWAVES)  // 256 t per wave
#define TT 16        // t-tile size

typedef _Float16 f16;
typedef __attribute__((ext_vector_type(4))) _Float16 f16x4;
typedef __attribute__((ext_vector_type(8))) _Float16 f16x8;
typedef __attribute__((ext_vector_type(4))) float f32x4;
typedef __attribute__((ext_vector_type(4))) short s16x4;

__device__ __forceinline__ float fexp2(float x) {
#if __has_builtin(__builtin_amdgcn_exp2f)
  return __builtin_amdgcn_exp2f(x);
#else
  return exp2f(x);
#endif
}

// float -> bf16 bits, RNE. bf16 (f32 exponent range) keeps exp2 of any logit
// finite — f16 P NaN'd on diagonal quadratic-form logits (R3 post-mortem).
__device__ __forceinline__ unsigned short f2bf(float f) {
  unsigned u = __builtin_bit_cast(unsigned, f);
  u += 0x7FFF + ((u >> 16) & 1);
  return (unsigned short)(u >> 16);
}

// Clifford Cl(3,0) structure shared by both kernels.
// blades[] is the bitmask<->index map (self-inverse involution).
__device__ __forceinline__ float cl_sign(int amask, int bmask) {
  int cnt = 0, aa = amask >> 1;
  while (aa) { cnt += __popc(aa & bmask); aa >>= 1; }
  return (cnt & 1) ? -1.f : 1.f;
}

// ---------------------------------------------------------------------------
// Kernel 1: fused {param-matrix build} + {Q/K/V projection & packing}.
//  LDS Pl layout (floats): [0..63] Mq*c0*0.5*log2e, [64..127] Mk,
//    [128..191] Mv, [256..263] bq', [264..271] bk, [272..279] bv
//  Qp[row][16] f16 = [qhi(8) | qlo(8)]   (B-operand rows; hi/lo split)
//  Kp[row][8]  f16 = khi                  (A-operand; lanes re-read via hi&1)
//  Vt[b][c][t] bf16 bits, c=0..8: rows 0-7 = V blades, row 8 = ones (denom)
// ---------------------------------------------------------------------------
__global__ __launch_bounds__(256) void ck_qkv(const float* __restrict__ x,
                                              const float* __restrict__ wq,
                                              const float* __restrict__ bq,
                                              const float* __restrict__ wk,
                                              const float* __restrict__ bk,
                                              const float* __restrict__ wv,
                                              const float* __restrict__ bv,
                                              f16* __restrict__ Qp,
                                              f16* __restrict__ Kp,
                                              unsigned short* __restrict__ Vt) {
  __shared__ float Pl[288];
  const int blades[8] = {0, 1, 2, 4, 3, 5, 6, 7};
  int tid = threadIdx.x;

  if (tid < 64) {
    int j = tid >> 3, k = tid & 7;
    int bj = blades[j];
    float mq = 0.f, mk = 0.f, mv = 0.f;
    for (int i = 0; i < 8; ++i) {
      int ai = blades[i];
      if (blades[ai ^ bj] != k) continue;
      float sgn = cl_sign(ai, bj);
      mq += sgn * wq[i]; mk += sgn * wk[i]; mv += sgn * wv[i];
    }
    float c0 = cl_sign(blades[k], blades[k]);  // diagonal of scalar-part table
    const float F = 0.72134752044448170368f;   // 0.5 * log2(e)
    Pl[tid]       = mq * c0 * F;
    Pl[64 + tid]  = mk;
    Pl[128 + tid] = mv;
    if (j == 0) {
      Pl[256 + k] = bq[k] * c0 * F;
      Pl[264 + k] = bk[k];
      Pl[272 + k] = bv[k];
    }
  }
  __syncthreads();

  int row = blockIdx.x * 256 + tid;  // grid sized exactly to B*S
  int b = row >> 12;
  int s = row & (SEQ - 1);
  const float4* x4 = (const float4*)(x + (size_t)row * 8);
  float4 xa = x4[0], xb = x4[1];
  float xr[8] = {xa.x, xa.y, xa.z, xa.w, xb.x, xb.y, xb.z, xb.w};
  float q[8], k[8], v[8];
#pragma unroll
  for (int c = 0; c < 8; ++c) { q[c] = Pl[256 + c]; k[c] = Pl[264 + c]; v[c] = Pl[272 + c]; }
#pragma unroll
  for (int j = 0; j < 8; ++j) {
    float xj = xr[j];
#pragma unroll
    for (int c = 0; c < 8; ++c) {
      q[c] = fmaf(xj, Pl[j * 8 + c], q[c]);
      k[c] = fmaf(xj, Pl[64 + j * 8 + c], k[c]);
      v[c] = fmaf(xj, Pl[128 + j * 8 + c], v[c]);
    }
  }
  f16x8 qa, qb, ka;
#pragma unroll
  for (int c = 0; c < 8; ++c) {
    f16 h = (f16)q[c];
    qa[c] = h;
    qb[c] = (f16)(q[c] - (float)h);
    ka[c] = (f16)k[c];
  }
  f16x8* qrow = (f16x8*)(Qp + (size_t)row * 16);
  qrow[0] = qa; qrow[1] = qb;
  *(f16x8*)(Kp + (size_t)row * 8) = ka;
  unsigned short* vtb = Vt + (size_t)b * 9 * SEQ;
#pragma unroll
  for (int c = 0; c < 8; ++c) vtb[c * SEQ + s] = f2bf(v[c]);
  vtb[8 * SEQ + s] = 0x3F80;  // 1.0 bf16
}

// ---------------------------------------------------------------------------
// Kernel 2: MFMA flash attention, no-max softmax (bf16 P: no overflow).
// One block = 32 s-rows; 16 waves t-split (256 t each), 2 blocks/CU
// (launch_bounds forces VGPR<=64 for 8 waves/SIMD).
// Per wave, per 16-t tile, per 16-s subtile g:
//   S^T = mfma_16x16x16f16(Kfrag, Qfrag[g], 0)
//     -> lane holds S[s=l&15][t0 + 4*(l>>4)+r], r=0..3
//   P = exp2(S) elementwise, f32 -> bf16  (exactly the B-frag of P^T for PV)
//   accT[g] = mfma_16x16x16bf16_1k(VaugTfrag, Pfrag, accT[g])
//     -> lane holds O^T[c=4*(l>>4)+r][s=l&15]; row c=8 is the denom l.
// Combine 16 wave-partials in LDS, normalize, fuse Mo clifford transform
// (Mo/bo recomputed in-block from wo/bo — no params kernel).
// ---------------------------------------------------------------------------
__global__ __launch_bounds__(1024, 8) void ck_attn(const f16* __restrict__ Qp,
                                                   const f16* __restrict__ Kp,
                                                   const unsigned short* __restrict__ Vt,
                                                   const float* __restrict__ wo,
                                                   const float* __restrict__ bo,
                                                   float* __restrict__ out) {
  __shared__ float Lo[TWAVES][SGRP][9];
  __shared__ float MoL[72];  // [0..63] Mo[j][k], [64..71] bo

  const int tid = threadIdx.x;
  const int w = tid >> 6;
  const int lane = tid & 63;
  const int lo = lane & 15, hi = lane >> 4;
  const int rowbase = blockIdx.x * SGRP;
  const int b = rowbase >> 12;

  if (tid < 64) {
    const int blades[8] = {0, 1, 2, 4, 3, 5, 6, 7};
    int j = tid >> 3, k = tid & 7;
    int bj = blades[j];
    float mo = 0.f;
    for (int i = 0; i < 8; ++i) {
      int ai = blades[i];
      if (blades[ai ^ bj] != k) continue;
      mo += cl_sign(ai, bj) * wo[i];
    }
    MoL[tid] = mo;
    if (j == 0) MoL[64 + k] = bo[k];
  }

  // Q fragments for the 2 s-subtiles (hoisted)
  f16x4 qf0 = *(const f16x4*)(Qp + (size_t)(rowbase + 0 * 16 + lo) * 16 + 4 * hi);
  f16x4 qf1 = *(const f16x4*)(Qp + (size_t)(rowbase + 1 * 16 + lo) * 16 + 4 * hi);

  f32x4 acc0 = {0.f, 0.f, 0.f, 0.f};
  f32x4 acc1 = acc0;
  const f32x4 zero = {0.f, 0.f, 0.f, 0.f};

  const f16* kbase = Kp + ((size_t)b * SEQ + w * TCHUNK + lo) * 8 + 4 * (hi & 1);
  const unsigned short* vbase =
      Vt + ((size_t)b * 9 + (lo < 9 ? lo : 8)) * SEQ + w * TCHUNK + 4 * hi;

#pragma unroll 2
  for (int it = 0; it < TCHUNK / TT; ++it) {
    f16x4 kf = *(const f16x4*)(kbase + it * TT * 8);
    s16x4 vf = {0, 0, 0, 0};
    if (lo < 9) vf = *(const s16x4*)(vbase + it * TT);

#define SUBTILE(QF, ACC)                                                       \
    {                                                                          \
      f32x4 s4 = __builtin_amdgcn_mfma_f32_16x16x16f16(kf, QF, zero, 0, 0, 0); \
      s16x4 pf;                                                                \
      pf[0] = (short)f2bf(fexp2(s4[0]));                                       \
      pf[1] = (short)f2bf(fexp2(s4[1]));                                       \
      pf[2] = (short)f2bf(fexp2(s4[2]));                                       \
      pf[3] = (short)f2bf(fexp2(s4[3]));                                       \
      ACC = __builtin_amdgcn_mfma_f32_16x16x16bf16_1k(vf, pf, ACC, 0, 0, 0);   \
    }
    SUBTILE(qf0, acc0)
    SUBTILE(qf1, acc1)
#undef SUBTILE
  }

  // write wave partials: lanes hi<2 carry O blades 0-7, lane hi==2,r=0 the denom
#define WRITEG(G, ACC)                                                       \
  {                                                                          \
    if (hi < 2) {                                                            \
      Lo[w][G * 16 + lo][4 * hi + 0] = ACC[0];                               \
      Lo[w][G * 16 + lo][4 * hi + 1] = ACC[1];                               \
      Lo[w][G * 16 + lo][4 * hi + 2] = ACC[2];                               \
      Lo[w][G * 16 + lo][4 * hi + 3] = ACC[3];                               \
    } else if (hi == 2) {                                                    \
      Lo[w][G * 16 + lo][8] = ACC[0];                                        \
    }                                                                        \
  }
  WRITEG(0, acc0)
  WRITEG(1, acc1)
#undef WRITEG
  __syncthreads();

  // stage 1: sum 16 wave-partials per (s, j); each cell has a unique owner
  if (tid < SGRP * 9) {
    int s = tid / 9, j = tid - s * 9;
    float sum = 0.f;
#pragma unroll
    for (int w2 = 0; w2 < TWAVES; ++w2) sum += Lo[w2][s][j];
    Lo[0][s][j] = sum;
  }
  __syncthreads();

  // stage 2: normalize + fused output clifford transform
  if (tid < SGRP * 8) {
    int s = tid >> 3, ko = tid & 7;
    float inv = 1.f / Lo[0][s][8];
    float a = MoL[64 + ko];
#pragma unroll
    for (int j = 0; j < 8; ++j) a = fmaf(Lo[0][s][j] * inv, MoL[j * 8 + ko], a);
    out[(size_t)(rowbase + s) * 8 + ko] = a;
  }
}

// ---------------------------------------------------------------------------
extern "C" void kernel_launch(void* const* d_in, const int* in_sizes, int n_in,
                              void* d_out, int out_size, void* d_ws, size_t ws_size,
                              hipStream_t stream) {
  const float* x  = (const float*)d_in[0];
  const float* wq = (const float*)d_in[1];
  const float* bq = (const float*)d_in[2];
  const float* wk = (const float*)d_in[3];
  const float* bk = (const float*)d_in[4];
  const float* wv = (const float*)d_in[5];
  const float* bv = (const float*)d_in[6];
  const float* wo = (const float*)d_in[7];
  const float* bo = (const float*)d_in[8];

  f16* Qp = (f16*)d_ws;                                 // [B*S][16] f16 = 512 KB
  f16* Kp = Qp + (size_t)NBATCH * SEQ * 16;             // [B*S][8]  f16 = 256 KB
  unsigned short* Vt = (unsigned short*)(Kp + (size_t)NBATCH * SEQ * 8);  // [B][9][S] bf16 = 288 KB
  float* outp = (float*)d_out;

  hipLaunchKernelGGL(ck_qkv, dim3(NBATCH * SEQ / 256), dim3(256), 0, stream,
                     x, wq, bq, wk, bk, wv, bv, Qp, Kp, Vt);
  hipLaunchKernelGGL(ck_attn, dim3(NBATCH * SEQ / SGRP), dim3(1024), 0, stream,
                     Qp, Kp, Vt, wo, bo, outp);
}